// Round 1
// baseline (199.587 us; speedup 1.0000x reference)
//
#include <hip/hip_runtime.h>
#include <stdint.h>

typedef __bf16 bf16;
typedef __bf16 bf16x8 __attribute__((ext_vector_type(8)));
typedef float  f32x4  __attribute__((ext_vector_type(4)));

#if __has_builtin(__builtin_amdgcn_exp2f)
#define EXP2F(x) __builtin_amdgcn_exp2f(x)
#else
#define EXP2F(x) exp2f(x)
#endif

// async global->LDS, 16B per lane; LDS dest must be wave-uniform base (lane*16 auto)
#define GLD_LDS16(g, l)                                                                    \
  __builtin_amdgcn_global_load_lds((const __attribute__((address_space(1))) uint32_t*)(g), \
                                   (__attribute__((address_space(3))) uint32_t*)(l), 16, 0, 0)

constexpr int Bn = 8192, Sn = 256, Rn = 8192;
constexpr int BM = 64, BK = 32, KP = 4;
constexpr int KLEN = Rn / KP;   // 2048
constexpr int FLD = 40;         // flux_lds padded row (bf16 elems): 80B, 16B-aligned, conflict-free

// ---------- prep kernels ----------

__global__ __launch_bounds__(256) void prep_params(
    const float* __restrict__ alpha, const float* __restrict__ beta,
    const float* __restrict__ gam, const int* __restrict__ rm,
    const int* __restrict__ rtype, float4* __restrict__ params) {
  int r = blockIdx.x * 256 + threadIdx.x;
  if (r >= Rn) return;
  float a = alpha[r], be = beta[r], g = gam[r];
  int ty = rtype[r];
  int i0 = rm[2 * r], i1 = rm[2 * r + 1];
  float A = a, P = 0.0f, Q = 0.0f;
  if (ty == 0) { P = be; Q = g; }           // rate = A * exp2(P*log2(T/300) - Q*log2e/T)
  else if (ty == 2) { A = a * expf(-g); }   // rate = A * fuv
  // ty == 1: rate = A * cr
  uint32_t bits = (uint32_t)i0 | ((uint32_t)i1 << 10) | ((uint32_t)ty << 20);
  params[r] = make_float4(A, P, Q, __uint_as_float(bits));
}

__global__ __launch_bounds__(256) void prep_perb(
    const float* __restrict__ temp, const float* __restrict__ cr,
    const float* __restrict__ fuv, float4* __restrict__ perb) {
  int b = blockIdx.x * 256 + threadIdx.x;
  if (b >= Bn) return;
  float T = temp[b];
  perb[b] = make_float4(log2f(T * (1.0f / 300.0f)), 1.4426950408889634f / T, cr[b], fuv[b]);
}

__global__ __launch_bounds__(256) void prep_inc(const float* __restrict__ inc,
                                                bf16* __restrict__ out) {
  size_t i = ((size_t)blockIdx.x * 256 + threadIdx.x) * 8;
  float4 v0 = *(const float4*)(inc + i);
  float4 v1 = *(const float4*)(inc + i + 4);
  bf16x8 o;
  o[0] = (bf16)v0.x; o[1] = (bf16)v0.y; o[2] = (bf16)v0.z; o[3] = (bf16)v0.w;
  o[4] = (bf16)v1.x; o[5] = (bf16)v1.y; o[6] = (bf16)v1.z; o[7] = (bf16)v1.w;
  *(bf16x8*)(out + i) = o;
}

// ---------- fused flux + GEMM ----------
// out[b][s] += sum_{k in kpart} flux[b][k] * incT[k][s]; A=flux (BMxBK), B=inc[s][k]
__global__ __launch_bounds__(256, 2) void flux_gemm(
    const float* __restrict__ abund, const float4* __restrict__ perb,
    const float4* __restrict__ params, const bf16* __restrict__ incb,
    float* __restrict__ out) {
  __shared__ bf16 ab_lds[257 * 64];    // [s][b_local], row 128B = 32 banks; row 256 = 1.0 pad
  __shared__ bf16 inc_lds[256 * BK];   // [n][k] rows of 64B (B-fragment order)
  __shared__ bf16 flux_lds[BM * FLD];  // [m][k] padded rows (A-fragment order)

  const int tid  = threadIdx.x;
  const int lane = tid & 63;
  const int w    = tid >> 6;                     // wave 0..3
  const int kp   = blockIdx.x & (KP - 1);
  const int m0   = (blockIdx.x >> 2) * BM;
  const int kstart = kp * KLEN;
  const int r16 = lane & 15, q = lane >> 4;

  // ---- stage abundances tile transposed to bf16 (once) ----
  {
    int bsub = tid >> 2;             // 0..63
    int scol = (tid & 3) * 64;
    const float* rowp = abund + (size_t)(m0 + bsub) * Sn + scol;
#pragma unroll
    for (int j = 0; j < 16; ++j) {
      float4 v = *(const float4*)(rowp + j * 4);
      int s = scol + j * 4;
      ab_lds[(s + 0) * 64 + bsub] = (bf16)v.x;
      ab_lds[(s + 1) * 64 + bsub] = (bf16)v.y;
      ab_lds[(s + 2) * 64 + bsub] = (bf16)v.z;
      ab_lds[(s + 3) * 64 + bsub] = (bf16)v.w;
    }
    if (tid < 64) ab_lds[256 * 64 + tid] = (bf16)1.0f;  // ones column (index S)
  }

  // per-b values for this thread's flux row (m = lane)
  float4 pb = perb[m0 + lane];
  const float l2t = pb.x, itv = pb.y, crv = pb.z, fuvv = pb.w;

  f32x4 acc[4][4];
#pragma unroll
  for (int i = 0; i < 4; ++i)
#pragma unroll
    for (int j = 0; j < 4; ++j) acc[i][j] = (f32x4)0.0f;

  for (int c = 0; c < KLEN / BK; ++c) {
    const int kb = kstart + c * BK;
    __syncthreads();  // prev MFMA frag reads done before LDS overwrite

    // stage incidence tile [256 x BK] bf16: wave w -> rows [w*64, w*64+64)
#pragma unroll
    for (int i = 0; i < 4; ++i) {
      int rrow = w * 64 + i * 16 + (lane >> 2);
      const bf16* g = incb + (size_t)rrow * Rn + kb + (lane & 3) * 8;
      bf16* l = inc_lds + (w * 64 + i * 16) * BK;  // wave-uniform base
      GLD_LDS16(g, l);
    }

    // flux tile: thread -> m = lane, k = w*8 + j
    {
      const float4* pch = params + kb + w * 8;
      bf16x8 fv;
#pragma unroll
      for (int j = 0; j < 8; ++j) {
        float4 pr = pch[j];
        uint32_t bits = __float_as_uint(pr.w);
        int i0 = bits & 1023;
        int i1 = (bits >> 10) & 1023;
        int ms = bits >> 20;
        float e = fmaf(pr.y, l2t, -pr.z * itv);
        float v = EXP2F(e);
        float mult = (ms == 1) ? crv : ((ms == 2) ? fuvv : 1.0f);
        float rate = pr.x * v * mult;
        float a0 = (float)ab_lds[i0 * 64 + lane];
        float a1 = (float)ab_lds[i1 * 64 + lane];
        fv[j] = (bf16)(rate * a0 * a1);
      }
      *(bf16x8*)(flux_lds + lane * FLD + w * 8) = fv;
    }

    __syncthreads();  // drains vmcnt (global_load_lds) + lgkm (ds writes)

    bf16x8 af[4], bfr[4];
#pragma unroll
    for (int mt = 0; mt < 4; ++mt)
      af[mt] = *(const bf16x8*)(flux_lds + (mt * 16 + r16) * FLD + q * 8);
#pragma unroll
    for (int nt = 0; nt < 4; ++nt)
      bfr[nt] = *(const bf16x8*)(inc_lds + (w * 64 + nt * 16 + r16) * BK + q * 8);
#pragma unroll
    for (int mt = 0; mt < 4; ++mt)
#pragma unroll
      for (int nt = 0; nt < 4; ++nt)
        acc[mt][nt] = __builtin_amdgcn_mfma_f32_16x16x32_bf16(af[mt], bfr[nt], acc[mt][nt], 0, 0, 0);
  }

  // epilogue: split-K partial -> atomic accumulate into zeroed out
#pragma unroll
  for (int mt = 0; mt < 4; ++mt)
#pragma unroll
    for (int nt = 0; nt < 4; ++nt) {
      int col = w * 64 + nt * 16 + r16;
      int row = m0 + mt * 16 + q * 4;
#pragma unroll
      for (int rg = 0; rg < 4; ++rg)
        atomicAdd(out + (size_t)(row + rg) * Sn + col, acc[mt][nt][rg]);
    }
}

// ---------- launch ----------
extern "C" void kernel_launch(void* const* d_in, const int* in_sizes, int n_in,
                              void* d_out, int out_size, void* d_ws, size_t ws_size,
                              hipStream_t stream) {
  // inputs: 0 time, 1 abundances, 2 temperature, 3 cr_rate, 4 fuv_rate,
  //         5 incidence, 6 alpha, 7 beta, 8 gamma, 9 reactant_multipliers, 10 rtype
  const float* abund = (const float*)d_in[1];
  const float* temp  = (const float*)d_in[2];
  const float* cr    = (const float*)d_in[3];
  const float* fuv   = (const float*)d_in[4];
  const float* inc   = (const float*)d_in[5];
  const float* alpha = (const float*)d_in[6];
  const float* beta  = (const float*)d_in[7];
  const float* gam   = (const float*)d_in[8];
  const int*   rm    = (const int*)d_in[9];
  const int*   rty   = (const int*)d_in[10];
  float* out = (float*)d_out;

  // ws layout: params float4[R] | perb float4[B] | inc bf16[S*R]  (~4.25 MB)
  float4* params = (float4*)d_ws;
  float4* perb   = params + Rn;
  bf16*   incb   = (bf16*)(perb + Bn);

  hipMemsetAsync(d_out, 0, (size_t)Bn * Sn * sizeof(float), stream);
  prep_params<<<Rn / 256, 256, 0, stream>>>(alpha, beta, gam, rm, rty, params);
  prep_perb<<<Bn / 256, 256, 0, stream>>>(temp, cr, fuv, perb);
  prep_inc<<<(Sn * Rn) / 2048, 256, 0, stream>>>(inc, incb);
  flux_gemm<<<(Bn / BM) * KP, 256, 0, stream>>>(abund, perb, params, incb, out);
}